// Round 13
// baseline (1256.980 us; speedup 1.0000x reference)
//
#include <hip/hip_runtime.h>
#include <hip/hip_bf16.h>

// ---------------------------------------------------------------------------
// Shapes: B=64, P=196, ENC=2048, E=H=A=512, V=10000, L=21 -> T=20
// GEMMs on MFMA via split-bf16 (hi+lo). features/att1 held in bf16.
// Discrete-launch loop, 4 dispatches/step: hgemm -> attn_fused64 (scores+
// softmax+awe+gate, ONE block per batch, zero redundant work) -> gates ->
// lstm. (grid.sync ~40us on MI355X; redundant-work fusion regressed.)
// att1: 128x64 tile, A bf16-hi, 2-deep pipeline (2 reg sets + 2x16KB LDS).
// Packed fragment layout (16-row tile x 32-k chunk -> 64 lanes x 8 bf16):
//   flat = (((mn>>4)*KC + (k>>5))*64 + ((k&31)>>3)*16 + (mn&15))*8 + (k&7)
// ---------------------------------------------------------------------------

#define TB 256

typedef __bf16 bf16x8 __attribute__((ext_vector_type(8)));
typedef float f32x4 __attribute__((ext_vector_type(4)));
typedef unsigned short u16x8 __attribute__((ext_vector_type(8)));
typedef unsigned short u16x4 __attribute__((ext_vector_type(4)));
typedef unsigned short ushort_t;

__device__ __forceinline__ ushort_t f2bf(float x) {
    unsigned u = __builtin_bit_cast(unsigned, x);
    u += 0x7fffu + ((u >> 16) & 1u);          // round-to-nearest-even
    return (ushort_t)(u >> 16);
}
__device__ __forceinline__ float bf2f(ushort_t b) {
    return __builtin_bit_cast(float, (unsigned)b << 16);
}
__device__ __forceinline__ void store_pack(
    ushort_t* __restrict__ Ph, ushort_t* __restrict__ Pl,
    int KC, int m, int k, float v)
{
    const size_t flat = ((((size_t)(m >> 4) * KC + (k >> 5)) * 64)
                         + ((k & 31) >> 3) * 16 + (m & 15)) * 8 + (k & 7);
    const ushort_t h = f2bf(v);
    Ph[flat] = h;
    Pl[flat] = f2bf(v - bf2f(h));
}

// ------------------------- fused weight pack kernel ------------------------
struct PackJobs {
    const float* W[7];
    ushort_t* Bh[7];
    ushort_t* Bl[7];
    int Nsrc[7], ntCount[7], KC[7], ntBase[7];
    int cum[8];
};

__global__ __launch_bounds__(TB) void pack_all(PackJobs J)
{
    const int blk = blockIdx.x;
    int j = 0;
    #pragma unroll
    for (int i = 1; i < 7; ++i) if (blk >= J.cum[i]) j = i;
    const int g = (blk - J.cum[j]) * TB + threadIdx.x;
    const int KC = J.KC[j];
    const int lane = g & 63;
    const int kc = (g >> 6) % KC;
    const int nt = g / (64 * KC);
    if (nt >= J.ntCount[j]) return;
    const int Nsrc = J.Nsrc[j];
    const float* W = J.W[j];
    const int n = nt * 16 + (lane & 15);
    const int kb = kc * 32 + (lane >> 4) * 8;
    u16x8 hv, lv;
    #pragma unroll
    for (int e = 0; e < 8; ++e) {
        const float x = (n < Nsrc) ? W[(size_t)(kb + e) * Nsrc + n] : 0.f;
        const ushort_t h = f2bf(x);
        hv[e] = h;
        lv[e] = f2bf(x - bf2f(h));
    }
    const size_t flat = (((size_t)(J.ntBase[j] + nt) * KC + kc) * 64 + lane) * 8;
    *(u16x8*)&J.Bh[j][flat] = hv;
    *(u16x8*)&J.Bl[j][flat] = lv;
}

// ------------------------- features fp32 -> bf16 cast ----------------------
__global__ __launch_bounds__(TB) void feat2bf(
    const float* __restrict__ f, ushort_t* __restrict__ fbf)
{
    const size_t i8 = ((size_t)blockIdx.x * TB + threadIdx.x) * 8;
    const float4 a = *(const float4*)&f[i8];
    const float4 b = *(const float4*)&f[i8 + 4];
    u16x8 v;
    v[0] = f2bf(a.x); v[1] = f2bf(a.y); v[2] = f2bf(a.z); v[3] = f2bf(a.w);
    v[4] = f2bf(b.x); v[5] = f2bf(b.y); v[6] = f2bf(b.z); v[7] = f2bf(b.w);
    *(u16x8*)&fbf[i8] = v;
}

// ------------------------- MFMA tile compute (A split hi/lo) ---------------
template<int MT, int NT, int WR, int WC>
__device__ __forceinline__ void mfma_tile(
    const ushort_t* lds, int wr, int wc, int lane,
    f32x4 acc[MT / WR][NT / WC])
{
    constexpr int MFR = MT / WR, NFR = NT / WC;
    bf16x8 ah[MFR], al[MFR];
    #pragma unroll
    for (int i = 0; i < MFR; ++i) {
        ah[i] = __builtin_bit_cast(bf16x8, *(const u16x8*)&lds[(wr * MFR + i) * 512 + lane * 8]);
        al[i] = __builtin_bit_cast(bf16x8, *(const u16x8*)&lds[(MT + wr * MFR + i) * 512 + lane * 8]);
    }
    #pragma unroll
    for (int j = 0; j < NFR; ++j) {
        const bf16x8 bh = __builtin_bit_cast(bf16x8, *(const u16x8*)&lds[(2 * MT + wc * NFR + j) * 512 + lane * 8]);
        const bf16x8 bl = __builtin_bit_cast(bf16x8, *(const u16x8*)&lds[(2 * MT + NT + wc * NFR + j) * 512 + lane * 8]);
        #pragma unroll
        for (int i = 0; i < MFR; ++i) {
            acc[i][j] = __builtin_amdgcn_mfma_f32_16x16x32_bf16(ah[i], bh, acc[i][j], 0, 0, 0);
            acc[i][j] = __builtin_amdgcn_mfma_f32_16x16x32_bf16(ah[i], bl, acc[i][j], 0, 0, 0);
            acc[i][j] = __builtin_amdgcn_mfma_f32_16x16x32_bf16(al[i], bh, acc[i][j], 0, 0, 0);
        }
    }
}

// ------------------------- generic packed MFMA GEMM ------------------------
template<int MT, int NT, int WR, int WC>
__global__ __launch_bounds__(TB) void gemm_mfma(
    const ushort_t* __restrict__ Ah, const ushort_t* __restrict__ Al,
    const ushort_t* __restrict__ Bh, const ushort_t* __restrict__ Bl,
    int KC, int kcPer,
    const float* __restrict__ bias,
    float* __restrict__ C, int ldc, int Ncols, size_t cPartStride)
{
    constexpr int MFR = MT / WR, NFR = NT / WC, CH = 2 * (MT + NT);
    __shared__ __align__(16) ushort_t lds[CH * 512];
    const int tid = threadIdx.x, wid = tid >> 6, lane = tid & 63;
    const int wr = wid / WC, wc = wid % WC;

    const int tot = gridDim.x * gridDim.y;
    const int lin = blockIdx.x + gridDim.x * blockIdx.y;
    const int q = tot >> 3, r = tot & 7;
    const int xcd = lin & 7, jj = lin >> 3;
    const int base = (xcd < r) ? xcd * (q + 1) : r * (q + 1) + (xcd - r) * q;
    const int lin2 = base + jj;
    const int nb = lin2 / gridDim.y;
    const int mb = lin2 % gridDim.y;

    const int kc0 = blockIdx.z * kcPer;

    f32x4 acc[MFR][NFR];
    #pragma unroll
    for (int i = 0; i < MFR; ++i)
        #pragma unroll
        for (int j = 0; j < NFR; ++j)
            acc[i][j] = f32x4{0.f, 0.f, 0.f, 0.f};

    for (int kc = kc0; kc < kc0 + kcPer; ++kc) {
        __syncthreads();
        #pragma unroll
        for (int cc = 0; cc < CH / 4; ++cc) {
            const int c = cc * 4 + wid;
            const ushort_t* src;
            if (c < MT)                src = Ah + ((size_t)(mb * MT + c) * KC + kc) * 512;
            else if (c < 2 * MT)       src = Al + ((size_t)(mb * MT + c - MT) * KC + kc) * 512;
            else if (c < 2 * MT + NT)  src = Bh + ((size_t)(nb * NT + c - 2 * MT) * KC + kc) * 512;
            else                       src = Bl + ((size_t)(nb * NT + c - 2 * MT - NT) * KC + kc) * 512;
            *(u16x8*)&lds[c * 512 + lane * 8] = *(const u16x8*)(src + lane * 8);
        }
        __syncthreads();
        mfma_tile<MT, NT, WR, WC>(lds, wr, wc, lane, acc);
    }

    C += (size_t)blockIdx.z * cPartStride;
    #pragma unroll
    for (int i = 0; i < MFR; ++i)
        #pragma unroll
        for (int j = 0; j < NFR; ++j) {
            const int col = nb * NT * 16 + (wc * NFR + j) * 16 + (lane & 15);
            if (col < Ncols) {
                const float bv = bias ? bias[col] : 0.f;
                const int rbase = mb * MT * 16 + (wr * MFR + i) * 16 + ((lane >> 4) << 2);
                #pragma unroll
                for (int r2 = 0; r2 < 4; ++r2)
                    C[(size_t)(rbase + r2) * ldc + col] = acc[i][j][r2] + bv;
            }
        }
}

// --------- att1 GEMM: 128x64 tile, A bf16-hi, 2-deep pipeline --------------
__global__ __launch_bounds__(TB) void gemm_att1(
    const ushort_t* __restrict__ fbf,
    const ushort_t* __restrict__ Bh, const ushort_t* __restrict__ Bl,
    const float* __restrict__ bias, ushort_t* __restrict__ att1bf)
{
    __shared__ __align__(16) ushort_t lds[2 * 16 * 512];   // 32 KB
    const int tid = threadIdx.x, wid = tid >> 6, lane = tid & 63;
    const int wr = wid >> 1, wc = wid & 1;

    const int lin = blockIdx.x + (blockIdx.y << 3);   // 784 = 8 * 98
    const int lin2 = (lin & 7) * 98 + (lin >> 3);
    const int nb = lin2 & 7, mb = lin2 >> 3;          // mb 0..97 (128 rows)

    f32x4 acc[4][2];
    #pragma unroll
    for (int i = 0; i < 4; ++i)
        #pragma unroll
        for (int j = 0; j < 2; ++j)
            acc[i][j] = f32x4{0.f, 0.f, 0.f, 0.f};

    const int akg = tid & 3;
    const size_t abase = (size_t)(mb * 128) * 2048;

    u16x8 rA[4], rB[4];

    auto issueTo = [&](int kc, u16x8* r) {
        #pragma unroll
        for (int cc = 0; cc < 2; ++cc) {
            const int c = cc * 4 + wid;               // 0..7
            const ushort_t* src = (c < 4)
                ? Bh + ((size_t)(nb * 4 + c) * 64 + kc) * 512
                : Bl + ((size_t)(nb * 4 + (c - 4)) * 64 + kc) * 512;
            r[cc] = *(const u16x8*)(src + lane * 8);
        }
        #pragma unroll
        for (int p = 0; p < 2; ++p) {
            const int row = (p * 256 + tid) >> 2;     // 0..127
            r[2 + p] = *(const u16x8*)&fbf[abase + (size_t)row * 2048 + (size_t)kc * 32 + akg * 8];
        }
    };
    auto commitFrom = [&](const u16x8* r, ushort_t* buf) {
        #pragma unroll
        for (int cc = 0; cc < 2; ++cc) {
            const int c = cc * 4 + wid;
            *(u16x8*)&buf[(8 + c) * 512 + lane * 8] = r[cc];
        }
        #pragma unroll
        for (int p = 0; p < 2; ++p) {
            const int row = (p * 256 + tid) >> 2;
            *(u16x8*)&buf[(row >> 4) * 512 + (akg * 16 + (row & 15)) * 8] = r[2 + p];
        }
    };
    auto compute = [&](const ushort_t* buf) {
        bf16x8 ah[4];
        #pragma unroll
        for (int i = 0; i < 4; ++i)
            ah[i] = __builtin_bit_cast(bf16x8, *(const u16x8*)&buf[(wr * 4 + i) * 512 + lane * 8]);
        #pragma unroll
        for (int j = 0; j < 2; ++j) {
            const bf16x8 bh = __builtin_bit_cast(bf16x8, *(const u16x8*)&buf[(8 + wc * 2 + j) * 512 + lane * 8]);
            const bf16x8 bl = __builtin_bit_cast(bf16x8, *(const u16x8*)&buf[(12 + wc * 2 + j) * 512 + lane * 8]);
            #pragma unroll
            for (int i = 0; i < 4; ++i) {
                acc[i][j] = __builtin_amdgcn_mfma_f32_16x16x32_bf16(ah[i], bh, acc[i][j], 0, 0, 0);
                acc[i][j] = __builtin_amdgcn_mfma_f32_16x16x32_bf16(ah[i], bl, acc[i][j], 0, 0, 0);
            }
        }
    };

    issueTo(0, rA);
    commitFrom(rA, lds);
    issueTo(1, rB);
    __syncthreads();

    for (int kc = 0; kc < 64; kc += 2) {
        if (kc + 2 < 64) issueTo(kc + 2, rA);
        compute(lds);
        commitFrom(rB, lds + 16 * 512);
        __syncthreads();
        if (kc + 3 < 64) issueTo(kc + 3, rB);
        compute(lds + 16 * 512);
        if (kc + 2 < 64) commitFrom(rA, lds);
        __syncthreads();
    }

    #pragma unroll
    for (int i = 0; i < 4; ++i)
        #pragma unroll
        for (int j = 0; j < 2; ++j) {
            const int col = nb * 64 + (wc * 2 + j) * 16 + (lane & 15);
            const float bv = bias[col];
            const int rbase = mb * 128 + (wr * 4 + i) * 16 + ((lane >> 4) << 2);
            #pragma unroll
            for (int r = 0; r < 4; ++r)
                att1bf[(size_t)(rbase + r) * 512 + col] = f2bf(acc[i][j][r] + bv);
        }
}

// ------------------------- fp32 GEMM (one-time h0/c0 only) -----------------
__device__ __forceinline__ void gemm_body(
    float (*As)[68], float (*Ws)[68],
    const float* __restrict__ A, int lda,
    const float* __restrict__ W, int ldw,
    float* __restrict__ C, int ldc,
    int nTile, int N, int K)
{
    const int tid = threadIdx.x;
    const int tn = tid & 15;
    const int tm = tid >> 4;
    const int n0 = nTile * 64;

    float acc[4][4] = {{0.f}};

    for (int k0 = 0; k0 < K; k0 += 32) {
        {
            int r  = tid >> 3;
            int cc = (tid & 7) * 4;
            #pragma unroll
            for (int rr = 0; rr < 64; rr += 32) {
                const float4 a = *(const float4*)&A[(size_t)(rr + r) * lda + (k0 + cc)];
                As[cc + 0][rr + r] = a.x;
                As[cc + 1][rr + r] = a.y;
                As[cc + 2][rr + r] = a.z;
                As[cc + 3][rr + r] = a.w;
            }
        }
        {
            int r  = tid >> 4;
            int cc = (tid & 15) * 4;
            #pragma unroll
            for (int rr = 0; rr < 32; rr += 16) {
                const float4 w = *(const float4*)&W[(size_t)(k0 + rr + r) * ldw + (n0 + cc)];
                *(float4*)&Ws[rr + r][cc] = w;
            }
        }
        __syncthreads();
        #pragma unroll
        for (int kk = 0; kk < 32; ++kk) {
            const float4 a = *(const float4*)&As[kk][tm * 4];
            const float4 w = *(const float4*)&Ws[kk][tn * 4];
            const float av[4] = {a.x, a.y, a.z, a.w};
            const float wv[4] = {w.x, w.y, w.z, w.w};
            #pragma unroll
            for (int i = 0; i < 4; ++i)
                #pragma unroll
                for (int j = 0; j < 4; ++j)
                    acc[i][j] = fmaf(av[i], wv[j], acc[i][j]);
        }
        __syncthreads();
    }

    #pragma unroll
    for (int i = 0; i < 4; ++i) {
        const int m = tm * 4 + i;
        #pragma unroll
        for (int j = 0; j < 4; ++j)
            C[(size_t)m * ldc + (n0 + tn * 4 + j)] = acc[i][j];
    }
}

__global__ __launch_bounds__(TB) void gemm_hc(
    const float* __restrict__ mean,
    const float* __restrict__ Wh0, const float* __restrict__ Wc0,
    float* __restrict__ h0p, float* __restrict__ c0p)
{
    __shared__ float As[32][68];
    __shared__ float Ws[32][68];
    const int ks = blockIdx.y & 7;
    const int which = blockIdx.y >> 3;
    const float* W = which ? Wc0 : Wh0;
    float* Cp = which ? c0p : h0p;
    gemm_body(As, Ws,
              mean + (size_t)ks * 256, 2048,
              W + (size_t)ks * 256 * 512, 512,
              Cp + (size_t)ks * 64 * 512, 512,
              blockIdx.x, 512, 256);
}

// ---- fused scores + softmax + awe + gate + pack : ONE block per batch -----
// 64 blocks x 512 threads. Scores computed ONCE per b (no redundancy);
// awe done in two 1024-col halves (smq = 32KB LDS).
__global__ __launch_bounds__(512) void attn_fused64(
    const ushort_t* __restrict__ att1bf,  // (64,196,512) bf16
    const float* __restrict__ hga,        // (4,64,4608): att2 0..511, gpre 512..2559
    const float* __restrict__ bd,         // (512,)
    const float* __restrict__ Wfull,      // (512,)
    const ushort_t* __restrict__ fbf,     // (64,196,2048) bf16
    const float* __restrict__ bfb,        // (2048,)
    ushort_t* __restrict__ gPh, ushort_t* __restrict__ gPl)
{
    const int b = blockIdx.x;
    const int tid = threadIdx.x, w = tid >> 6, lane = tid & 63;

    __shared__ float att2[512];
    __shared__ float wf[512];
    __shared__ float sc[200];
    __shared__ float redm[8], reds[8];
    __shared__ float smq[8][1024];        // 32 KB

    // stage1: att2 = bd + sum of 4 partials; wf
    {
        float v = bd[tid];
        #pragma unroll
        for (int s = 0; s < 4; ++s)
            v += hga[(size_t)s * 64 * 4608 + (size_t)b * 4608 + tid];
        att2[tid] = v;
        wf[tid] = Wfull[tid];
    }
    __syncthreads();

    // stage2: scores, each wave covers its p-range once
    const int p0 = (w < 4) ? w * 25 : 100 + (w - 4) * 24;
    const int pn = (w < 4) ? 25 : 24;
    const int k0 = lane * 8;
    float a2r[8], wfr[8];
    #pragma unroll
    for (int e = 0; e < 8; ++e) { a2r[e] = att2[k0 + e]; wfr[e] = wf[k0 + e]; }
    for (int pp = 0; pp < pn; ++pp) {
        const int p = p0 + pp;
        const u16x8 v = *(const u16x8*)&att1bf[((size_t)b * 196 + p) * 512 + k0];
        float s = 0.f;
        #pragma unroll
        for (int e = 0; e < 8; ++e)
            s = fmaf(fmaxf(bf2f(v[e]) + a2r[e], 0.f), wfr[e], s);
        #pragma unroll
        for (int o = 32; o; o >>= 1) s += __shfl_xor(s, o);
        if (lane == 0) sc[p] = s;
    }
    __syncthreads();

    // stage3: softmax over 196 (alpha in place in sc)
    const float sv = (tid < 196) ? sc[tid] : -1e30f;
    float m = sv;
    #pragma unroll
    for (int o = 32; o; o >>= 1) m = fmaxf(m, __shfl_xor(m, o));
    if (lane == 0) redm[w] = m;
    __syncthreads();
    m = redm[0];
    #pragma unroll
    for (int i = 1; i < 8; ++i) m = fmaxf(m, redm[i]);
    const float e = (tid < 196) ? expf(sv - m) : 0.f;
    float s = e;
    #pragma unroll
    for (int o = 32; o; o >>= 1) s += __shfl_xor(s, o);
    if (lane == 0) reds[w] = s;
    __syncthreads();
    s = reds[0];
    #pragma unroll
    for (int i = 1; i < 8; ++i) s += reds[i];
    if (tid < 196) sc[tid] = e / s;
    __syncthreads();

    // stage4+5: awe + gate + pack, two 1024-col halves
    #pragma unroll
    for (int half = 0; half < 2; ++half) {
        const int colbase = half * 1024;
        const ushort_t* f = fbf + (size_t)b * 196 * 2048 + colbase + lane * 8;
        float acc[16];
        #pragma unroll
        for (int x = 0; x < 16; ++x) acc[x] = 0.f;
        for (int pp = 0; pp < pn; ++pp) {
            const float wgt = sc[p0 + pp];
            const u16x8 v0 = *(const u16x8*)&f[(size_t)(p0 + pp) * 2048];
            const u16x8 v1 = *(const u16x8*)&f[(size_t)(p0 + pp) * 2048 + 512];
            #pragma unroll
            for (int ee = 0; ee < 8; ++ee) {
                acc[ee]     = fmaf(wgt, bf2f(v0[ee]), acc[ee]);
                acc[8 + ee] = fmaf(wgt, bf2f(v1[ee]), acc[8 + ee]);
            }
        }
        *(f32x4*)&smq[w][lane * 8]           = f32x4{acc[0], acc[1], acc[2], acc[3]};
        *(f32x4*)&smq[w][lane * 8 + 4]       = f32x4{acc[4], acc[5], acc[6], acc[7]};
        *(f32x4*)&smq[w][512 + lane * 8]     = f32x4{acc[8], acc[9], acc[10], acc[11]};
        *(f32x4*)&smq[w][512 + lane * 8 + 4] = f32x4{acc[12], acc[13], acc[14], acc[15]};
        __syncthreads();

        #pragma unroll
        for (int x = tid; x < 1024; x += 512) {
            float a = smq[0][x];
            #pragma unroll
            for (int i = 1; i < 8; ++i) a += smq[i][x];
            const int cg = colbase + x;
            float gp = bfb[cg];
            #pragma unroll
            for (int ss = 0; ss < 4; ++ss)
                gp += hga[(size_t)ss * 64 * 4608 + (size_t)b * 4608 + 512 + cg];
            const float gate = 1.f / (1.f + expf(-gp));
            store_pack(gPh, gPl, 64, b, cg, gate * a);
        }
        __syncthreads();
    }
}

// ------------------------- LSTM pointwise ----------------------------------
__global__ __launch_bounds__(TB) void lstm_pw(
    const float* __restrict__ gates_part,  // (8,64,2048)
    const float* __restrict__ hga_part,    // (4,64,4608), gh = cols 2560..4607
    const float* __restrict__ eW,          // (64,20,2048), includes b_ih
    const float* __restrict__ b_hh,        // (2048,)
    int t,
    float* __restrict__ c,                 // (64,512)
    ushort_t* __restrict__ hPh, ushort_t* __restrict__ hPl,
    ushort_t* __restrict__ sPh, ushort_t* __restrict__ sPl)
{
    const int idx = blockIdx.x * TB + threadIdx.x;   // 0..32767
    const int b = idx >> 9;
    const int j = idx & 511;

    float g[4];
    #pragma unroll
    for (int comp = 0; comp < 4; ++comp) {
        const int col = comp * 512 + j;
        float v = b_hh[col] + eW[((size_t)b * 20 + t) * 2048 + col];
        #pragma unroll
        for (int s = 0; s < 8; ++s)
            v += gates_part[(size_t)s * 64 * 2048 + (size_t)b * 2048 + col];
        #pragma unroll
        for (int s = 0; s < 4; ++s)
            v += hga_part[(size_t)s * 64 * 4608 + (size_t)b * 4608 + 2560 + col];
        g[comp] = v;
    }
    const float si = 1.f / (1.f + expf(-g[0]));
    const float sf = 1.f / (1.f + expf(-g[1]));
    const float gg = tanhf(g[2]);
    const float so = 1.f / (1.f + expf(-g[3]));
    const float cn = sf * c[idx] + si * gg;
    c[idx] = cn;
    const float hn = so * tanhf(cn);
    store_pack(hPh, hPl, 16, b, j, hn);
    store_pack(sPh, sPl, 16, b * 20 + t, j, hn);
}

// ------------------------- precompute helpers ------------------------------
__global__ __launch_bounds__(TB) void mean_feat_bf(
    const ushort_t* __restrict__ fbf, float* __restrict__ mean_enc)
{
    const int b = blockIdx.y;
    const int e = blockIdx.x * TB + threadIdx.x;
    const ushort_t* f = fbf + (size_t)b * 196 * 2048 + e;
    float s = 0.f;
    #pragma unroll 4
    for (int p = 0; p < 196; ++p) s += bf2f(f[(size_t)p * 2048]);
    mean_enc[b * 2048 + e] = s * (1.f / 196.f);
}

__global__ __launch_bounds__(TB) void gather_emb_pack(
    const int* __restrict__ captions,
    const float* __restrict__ emb,
    ushort_t* __restrict__ Ph, ushort_t* __restrict__ Pl)
{
    const int bt = blockIdx.x;          // 0..1279
    const int b = bt / 20;
    const int t = bt % 20;
    const int tok = captions[b * 21 + t];
    for (int e = threadIdx.x; e < 512; e += TB)
        store_pack(Ph, Pl, 16, bt, e, emb[(size_t)tok * 512 + e]);
}

__global__ __launch_bounds__(TB) void reduce_hc(
    const float* __restrict__ h0p, const float* __restrict__ c0p,
    const float* __restrict__ bh0, const float* __restrict__ bc0,
    ushort_t* __restrict__ hPh, ushort_t* __restrict__ hPl,
    float* __restrict__ c)
{
    const int idx = blockIdx.x * TB + threadIdx.x;   // 0..65535
    const int half = idx >> 15;
    const int i = idx & 32767;
    const int j = i & 511;
    const float* P = half ? c0p : h0p;
    float v = half ? bc0[j] : bh0[j];
    #pragma unroll
    for (int s = 0; s < 8; ++s) v += P[(size_t)s * 64 * 512 + i];
    if (half) c[i] = v;
    else      store_pack(hPh, hPl, 16, i >> 9, j, v);
}

// ---------------------------------------------------------------------------
extern "C" void kernel_launch(void* const* d_in, const int* in_sizes, int n_in,
                              void* d_out, int out_size, void* d_ws, size_t ws_size,
                              hipStream_t stream)
{
    const float* features  = (const float*)d_in[0];
    const int*   captions  = (const int*)  d_in[1];
    const float* W_enc_att = (const float*)d_in[2];
    const float* b_enc_att = (const float*)d_in[3];
    const float* W_dec_att = (const float*)d_in[4];
    const float* b_dec_att = (const float*)d_in[5];
    const float* W_full    = (const float*)d_in[6];
    // d_in[7] = b_full : uniform shift -> softmax invariant, unused
    const float* emb       = (const float*)d_in[8];
    const float* W_ih      = (const float*)d_in[9];
    const float* W_hh      = (const float*)d_in[10];
    const float* b_ih      = (const float*)d_in[11];
    const float* b_hh      = (const float*)d_in[12];
    const float* W_init_h  = (const float*)d_in[13];
    const float* b_init_h  = (const float*)d_in[14];
    const float* W_init_c  = (const float*)d_in[15];
    const float* b_init_c  = (const float*)d_in[16];
    const float* W_fbeta   = (const float*)d_in[17];
    const float* b_fbeta   = (const float*)d_in[18];
    const float* W_fc      = (const float*)d_in[19];
    const float* b_fc      = (const float*)d_in[20];
    float* out = (float*)d_out;
    (void)ws_size;

    float* ws = (float*)d_ws;
    size_t off = 0;
    auto alloc  = [&](size_t n) { float* p = ws + off; off += n; return p; };
    auto ualloc = [&](size_t n) { ushort_t* p = (ushort_t*)(ws + off); off += (n + 1) / 2; return p; };

    float* eW     = alloc((size_t)64 * 20 * 2048);
    float* mean   = alloc(64 * 2048);
    float* hga    = alloc((size_t)4 * 64 * 4608);
    float* gatesp = alloc((size_t)8 * 64 * 2048);
    float* c      = alloc(64 * 512);

    ushort_t* fbf    = ualloc((size_t)12544 * 2048);   // features bf16 (51.4 MB)
    ushort_t* att1bf = ualloc((size_t)12544 * 512);    // att1 bf16   (12.8 MB)
    ushort_t* WencH = ualloc((size_t)32 * 64 * 512);   // W_enc_att  (K2048, N512)
    ushort_t* WencL = ualloc((size_t)32 * 64 * 512);
    ushort_t* WtopH = ualloc((size_t)128 * 16 * 512);  // W_ih[:512] (K512, N2048)
    ushort_t* WtopL = ualloc((size_t)128 * 16 * 512);
    ushort_t* Wih2H = ualloc((size_t)128 * 64 * 512);  // W_ih[512:] (K2048, N2048)
    ushort_t* Wih2L = ualloc((size_t)128 * 64 * 512);
    ushort_t* WdfhH = ualloc((size_t)288 * 16 * 512);  // [Wd|Wf|Wh] (K512, N4608)
    ushort_t* WdfhL = ualloc((size_t)288 * 16 * 512);
    ushort_t* WfcH  = ualloc((size_t)632 * 16 * 512);  // W_fc       (K512, N10000->10112)
    ushort_t* WfcL  = ualloc((size_t)632 * 16 * 512);
    ushort_t* embsH = ualloc((size_t)80 * 16 * 512);   // embs  (M1280, K512)
    ushort_t* embsL = ualloc((size_t)80 * 16 * 512);
    ushort_t* hPh   = ualloc((size_t)4 * 16 * 512);    // h     (M64, K512)
    ushort_t* hPl   = ualloc((size_t)4 * 16 * 512);
    ushort_t* gPh   = ualloc((size_t)4 * 64 * 512);    // gated (M64, K2048)
    ushort_t* gPl   = ualloc((size_t)4 * 64 * 512);
    ushort_t* sPh   = ualloc((size_t)80 * 16 * 512);   // hseq  (M1280, K512)
    ushort_t* sPl   = ualloc((size_t)80 * 16 * 512);

    // one-time h0/c0 partials reuse step buffers (consumed before loop)
    float* h0p = hga;      // 8*64*512 <= 4*64*4608
    float* c0p = gatesp;   // 8*64*512 <= 8*64*2048

    // ---- pack all weights in ONE kernel ----
    PackJobs J;
    J.W[0]=W_enc_att;               J.Bh[0]=WencH; J.Bl[0]=WencL; J.Nsrc[0]=512;   J.ntCount[0]=32;  J.KC[0]=64; J.ntBase[0]=0;
    J.W[1]=W_ih;                    J.Bh[1]=WtopH; J.Bl[1]=WtopL; J.Nsrc[1]=2048;  J.ntCount[1]=128; J.KC[1]=16; J.ntBase[1]=0;
    J.W[2]=W_ih + (size_t)512*2048; J.Bh[2]=Wih2H; J.Bl[2]=Wih2L; J.Nsrc[2]=2048;  J.ntCount[2]=128; J.KC[2]=64; J.ntBase[2]=0;
    J.W[3]=W_dec_att;               J.Bh[3]=WdfhH; J.Bl[3]=WdfhL; J.Nsrc[3]=512;   J.ntCount[3]=32;  J.KC[3]=16; J.ntBase[3]=0;
    J.W[4]=W_fbeta;                 J.Bh[4]=WdfhH; J.Bl[4]=WdfhL; J.Nsrc[4]=2048;  J.ntCount[4]=128; J.KC[4]=16; J.ntBase[4]=32;
    J.W[5]=W_hh;                    J.Bh[5]=WdfhH; J.Bl[5]=WdfhL; J.Nsrc[5]=2048;  J.ntCount[5]=128; J.KC[5]=16; J.ntBase[5]=160;
    J.W[6]=W_fc;                    J.Bh[6]=WfcH;  J.Bl[6]=WfcL;  J.Nsrc[6]=10000; J.ntCount[6]=632; J.KC[6]=16; J.ntBase[6]=0;
    {
        int cum = 0;
        const int blks[7] = {512, 512, 2048, 128, 512, 512, 2528};
        for (int i = 0; i < 7; ++i) { J.cum[i] = cum; cum += blks[i]; }
        J.cum[7] = cum;
        pack_all<<<cum, TB, 0, stream>>>(J);
    }

    // ---- precompute (step-invariant) ----
    feat2bf<<<12544, TB, 0, stream>>>(features, fbf);
    gather_emb_pack<<<1280, TB, 0, stream>>>(captions, emb, embsH, embsL);
    mean_feat_bf<<<dim3(8, 64), TB, 0, stream>>>(fbf, mean);
    gemm_hc<<<dim3(8, 16), TB, 0, stream>>>(mean, W_init_h, W_init_c, h0p, c0p);
    reduce_hc<<<256, TB, 0, stream>>>(h0p, c0p, b_init_h, b_init_c, hPh, hPl, c);
    // att1 = features @ W_enc_att + b -> bf16 : (12544 x 512), K=2048
    gemm_att1<<<dim3(8, 98), TB, 0, stream>>>(fbf, WencH, WencL, b_enc_att, att1bf);
    // eW = embs @ W_ih[:512] + b_ih : (1280 x 2048), K=512
    gemm_mfma<8, 8, 2, 2><<<dim3(16, 10, 1), TB, 0, stream>>>(
        embsH, embsL, WtopH, WtopL, 16, 16, b_ih, eW, 2048, 2048, 0);

    // ---- sequential decode (4 dispatches/step) ----
    for (int t = 0; t < 20; ++t) {
        // hga[ks] = h @ [Wd|Wf|Wh] partials : (64 x 4608), K=512 split 4
        gemm_mfma<4, 8, 2, 2><<<dim3(36, 1, 4), TB, 0, stream>>>(
            hPh, hPl, WdfhH, WdfhL, 16, 4, nullptr, hga, 4608, 4608, (size_t)64 * 4608);
        // fused scores+softmax+awe+gate (one block per batch, no redundancy)
        attn_fused64<<<64, 512, 0, stream>>>(
            att1bf, hga, b_dec_att, W_full, fbf, b_fbeta, gPh, gPl);
        // gatesp[ks] = gated @ W_ih[512:] partials : (64 x 2048), K=2048 split 8
        gemm_mfma<4, 8, 2, 2><<<dim3(16, 1, 8), TB, 0, stream>>>(
            gPh, gPl, Wih2H, Wih2L, 64, 8, nullptr, gatesp, 2048, 2048, (size_t)64 * 2048);
        lstm_pw<<<128, TB, 0, stream>>>(gatesp, hga, eW, b_hh, t, c, hPh, hPl, sPh, sPl);
    }

    // preds = hseq @ W_fc + b_fc : (1280 x 10000), K=512
    gemm_mfma<8, 8, 2, 2><<<dim3(79, 10, 1), TB, 0, stream>>>(
        sPh, sPl, WfcH, WfcL, 16, 16, b_fc, out, 10000, 10000, 0);
}

// Round 14
// 1035.351 us; speedup vs baseline: 1.2141x; 1.2141x over previous
//
#include <hip/hip_runtime.h>
#include <hip/hip_bf16.h>

// ---------------------------------------------------------------------------
// Shapes: B=64, P=196, ENC=2048, E=H=A=512, V=10000, L=21 -> T=20
// GEMMs on MFMA via split-bf16 (hi+lo). features/att1 held in bf16.
// Discrete-launch loop, 5 dispatches/step (round-9/11 structure — measured
// floor: grid.sync ~40us/sync on MI355X; redundant-work fusion +3us/step;
// narrow fusion loses awe parallelism). att1: 128x128 tile, A bf16-hi,
// 2-deep pipeline (2 reg sets + 2x24KB LDS buffers).
// Packed fragment layout (16-row tile x 32-k chunk -> 64 lanes x 8 bf16):
//   flat = (((mn>>4)*KC + (k>>5))*64 + ((k&31)>>3)*16 + (mn&15))*8 + (k&7)
// ---------------------------------------------------------------------------

#define TB 256

typedef __bf16 bf16x8 __attribute__((ext_vector_type(8)));
typedef float f32x4 __attribute__((ext_vector_type(4)));
typedef unsigned short u16x8 __attribute__((ext_vector_type(8)));
typedef unsigned short u16x4 __attribute__((ext_vector_type(4)));
typedef unsigned short ushort_t;

__device__ __forceinline__ ushort_t f2bf(float x) {
    unsigned u = __builtin_bit_cast(unsigned, x);
    u += 0x7fffu + ((u >> 16) & 1u);          // round-to-nearest-even
    return (ushort_t)(u >> 16);
}
__device__ __forceinline__ float bf2f(ushort_t b) {
    return __builtin_bit_cast(float, (unsigned)b << 16);
}
__device__ __forceinline__ void store_pack(
    ushort_t* __restrict__ Ph, ushort_t* __restrict__ Pl,
    int KC, int m, int k, float v)
{
    const size_t flat = ((((size_t)(m >> 4) * KC + (k >> 5)) * 64)
                         + ((k & 31) >> 3) * 16 + (m & 15)) * 8 + (k & 7);
    const ushort_t h = f2bf(v);
    Ph[flat] = h;
    Pl[flat] = f2bf(v - bf2f(h));
}

// ------------------------- fused weight pack kernel ------------------------
struct PackJobs {
    const float* W[7];
    ushort_t* Bh[7];
    ushort_t* Bl[7];
    int Nsrc[7], ntCount[7], KC[7], ntBase[7];
    int cum[8];
};

__global__ __launch_bounds__(TB) void pack_all(PackJobs J)
{
    const int blk = blockIdx.x;
    int j = 0;
    #pragma unroll
    for (int i = 1; i < 7; ++i) if (blk >= J.cum[i]) j = i;
    const int g = (blk - J.cum[j]) * TB + threadIdx.x;
    const int KC = J.KC[j];
    const int lane = g & 63;
    const int kc = (g >> 6) % KC;
    const int nt = g / (64 * KC);
    if (nt >= J.ntCount[j]) return;
    const int Nsrc = J.Nsrc[j];
    const float* W = J.W[j];
    const int n = nt * 16 + (lane & 15);
    const int kb = kc * 32 + (lane >> 4) * 8;
    u16x8 hv, lv;
    #pragma unroll
    for (int e = 0; e < 8; ++e) {
        const float x = (n < Nsrc) ? W[(size_t)(kb + e) * Nsrc + n] : 0.f;
        const ushort_t h = f2bf(x);
        hv[e] = h;
        lv[e] = f2bf(x - bf2f(h));
    }
    const size_t flat = (((size_t)(J.ntBase[j] + nt) * KC + kc) * 64 + lane) * 8;
    *(u16x8*)&J.Bh[j][flat] = hv;
    *(u16x8*)&J.Bl[j][flat] = lv;
}

// ------------------------- features fp32 -> bf16 cast ----------------------
__global__ __launch_bounds__(TB) void feat2bf(
    const float* __restrict__ f, ushort_t* __restrict__ fbf)
{
    const size_t i8 = ((size_t)blockIdx.x * TB + threadIdx.x) * 8;
    const float4 a = *(const float4*)&f[i8];
    const float4 b = *(const float4*)&f[i8 + 4];
    u16x8 v;
    v[0] = f2bf(a.x); v[1] = f2bf(a.y); v[2] = f2bf(a.z); v[3] = f2bf(a.w);
    v[4] = f2bf(b.x); v[5] = f2bf(b.y); v[6] = f2bf(b.z); v[7] = f2bf(b.w);
    *(u16x8*)&fbf[i8] = v;
}

// ------------------------- MFMA tile compute (A split hi/lo) ---------------
template<int MT, int NT, int WR, int WC>
__device__ __forceinline__ void mfma_tile(
    const ushort_t* lds, int wr, int wc, int lane,
    f32x4 acc[MT / WR][NT / WC])
{
    constexpr int MFR = MT / WR, NFR = NT / WC;
    bf16x8 ah[MFR], al[MFR];
    #pragma unroll
    for (int i = 0; i < MFR; ++i) {
        ah[i] = __builtin_bit_cast(bf16x8, *(const u16x8*)&lds[(wr * MFR + i) * 512 + lane * 8]);
        al[i] = __builtin_bit_cast(bf16x8, *(const u16x8*)&lds[(MT + wr * MFR + i) * 512 + lane * 8]);
    }
    #pragma unroll
    for (int j = 0; j < NFR; ++j) {
        const bf16x8 bh = __builtin_bit_cast(bf16x8, *(const u16x8*)&lds[(2 * MT + wc * NFR + j) * 512 + lane * 8]);
        const bf16x8 bl = __builtin_bit_cast(bf16x8, *(const u16x8*)&lds[(2 * MT + NT + wc * NFR + j) * 512 + lane * 8]);
        #pragma unroll
        for (int i = 0; i < MFR; ++i) {
            acc[i][j] = __builtin_amdgcn_mfma_f32_16x16x32_bf16(ah[i], bh, acc[i][j], 0, 0, 0);
            acc[i][j] = __builtin_amdgcn_mfma_f32_16x16x32_bf16(ah[i], bl, acc[i][j], 0, 0, 0);
            acc[i][j] = __builtin_amdgcn_mfma_f32_16x16x32_bf16(al[i], bh, acc[i][j], 0, 0, 0);
        }
    }
}

// ------------------------- generic packed MFMA GEMM ------------------------
template<int MT, int NT, int WR, int WC>
__global__ __launch_bounds__(TB) void gemm_mfma(
    const ushort_t* __restrict__ Ah, const ushort_t* __restrict__ Al,
    const ushort_t* __restrict__ Bh, const ushort_t* __restrict__ Bl,
    int KC, int kcPer,
    const float* __restrict__ bias,
    float* __restrict__ C, int ldc, int Ncols, size_t cPartStride)
{
    constexpr int MFR = MT / WR, NFR = NT / WC, CH = 2 * (MT + NT);
    __shared__ __align__(16) ushort_t lds[CH * 512];
    const int tid = threadIdx.x, wid = tid >> 6, lane = tid & 63;
    const int wr = wid / WC, wc = wid % WC;

    const int tot = gridDim.x * gridDim.y;
    const int lin = blockIdx.x + gridDim.x * blockIdx.y;
    const int q = tot >> 3, r = tot & 7;
    const int xcd = lin & 7, jj = lin >> 3;
    const int base = (xcd < r) ? xcd * (q + 1) : r * (q + 1) + (xcd - r) * q;
    const int lin2 = base + jj;
    const int nb = lin2 / gridDim.y;
    const int mb = lin2 % gridDim.y;

    const int kc0 = blockIdx.z * kcPer;

    f32x4 acc[MFR][NFR];
    #pragma unroll
    for (int i = 0; i < MFR; ++i)
        #pragma unroll
        for (int j = 0; j < NFR; ++j)
            acc[i][j] = f32x4{0.f, 0.f, 0.f, 0.f};

    for (int kc = kc0; kc < kc0 + kcPer; ++kc) {
        __syncthreads();
        #pragma unroll
        for (int cc = 0; cc < CH / 4; ++cc) {
            const int c = cc * 4 + wid;
            const ushort_t* src;
            if (c < MT)                src = Ah + ((size_t)(mb * MT + c) * KC + kc) * 512;
            else if (c < 2 * MT)       src = Al + ((size_t)(mb * MT + c - MT) * KC + kc) * 512;
            else if (c < 2 * MT + NT)  src = Bh + ((size_t)(nb * NT + c - 2 * MT) * KC + kc) * 512;
            else                       src = Bl + ((size_t)(nb * NT + c - 2 * MT - NT) * KC + kc) * 512;
            *(u16x8*)&lds[c * 512 + lane * 8] = *(const u16x8*)(src + lane * 8);
        }
        __syncthreads();
        mfma_tile<MT, NT, WR, WC>(lds, wr, wc, lane, acc);
    }

    C += (size_t)blockIdx.z * cPartStride;
    #pragma unroll
    for (int i = 0; i < MFR; ++i)
        #pragma unroll
        for (int j = 0; j < NFR; ++j) {
            const int col = nb * NT * 16 + (wc * NFR + j) * 16 + (lane & 15);
            if (col < Ncols) {
                const float bv = bias ? bias[col] : 0.f;
                const int rbase = mb * MT * 16 + (wr * MFR + i) * 16 + ((lane >> 4) << 2);
                #pragma unroll
                for (int r2 = 0; r2 < 4; ++r2)
                    C[(size_t)(rbase + r2) * ldc + col] = acc[i][j][r2] + bv;
            }
        }
}

// --------- att1 GEMM: 128x128 tile, A bf16-hi, 2-deep pipeline -------------
// Two register sets (rA/rB) + 2 LDS buffers: loads issued at iter k are
// consumed at iter k+2, so each batch gets a full iteration of latency cover.
// LDS 48KB -> 3 blocks/CU. grid (4, 98), XCD-bijective swizzle.
__global__ __launch_bounds__(TB) void gemm_att1(
    const ushort_t* __restrict__ fbf,
    const ushort_t* __restrict__ Bh, const ushort_t* __restrict__ Bl,
    const float* __restrict__ bias, ushort_t* __restrict__ att1bf)
{
    __shared__ __align__(16) ushort_t lds[2 * 24 * 512];   // 48 KB
    const int tid = threadIdx.x, wid = tid >> 6, lane = tid & 63;
    const int wr = wid >> 1, wc = wid & 1;

    const int lin = blockIdx.x + (blockIdx.y << 2);   // 392 = 8 * 49
    const int lin2 = (lin & 7) * 49 + (lin >> 3);
    const int nb = lin2 & 3, mb = lin2 >> 2;          // mb 0..97 (128 rows)

    f32x4 acc[4][4];
    #pragma unroll
    for (int i = 0; i < 4; ++i)
        #pragma unroll
        for (int j = 0; j < 4; ++j)
            acc[i][j] = f32x4{0.f, 0.f, 0.f, 0.f};

    const int akg = tid & 3;                          // A staging map
    const size_t abase = (size_t)(mb * 128) * 2048;

    u16x8 rA[6], rB[6];

    auto issueTo = [&](int kc, u16x8* r) {
        #pragma unroll
        for (int cc = 0; cc < 4; ++cc) {
            const int c = cc * 4 + wid;               // 0..15
            const ushort_t* src = (c < 8)
                ? Bh + ((size_t)(nb * 8 + c) * 64 + kc) * 512
                : Bl + ((size_t)(nb * 8 + (c - 8)) * 64 + kc) * 512;
            r[cc] = *(const u16x8*)(src + lane * 8);
        }
        #pragma unroll
        for (int p = 0; p < 2; ++p) {
            const int row = (p * 256 + tid) >> 2;
            r[4 + p] = *(const u16x8*)&fbf[abase + (size_t)row * 2048 + (size_t)kc * 32 + akg * 8];
        }
    };
    auto commitFrom = [&](const u16x8* r, ushort_t* buf) {
        #pragma unroll
        for (int cc = 0; cc < 4; ++cc) {
            const int c = cc * 4 + wid;
            *(u16x8*)&buf[(8 + c) * 512 + lane * 8] = r[cc];
        }
        #pragma unroll
        for (int p = 0; p < 2; ++p) {
            const int row = (p * 256 + tid) >> 2;
            *(u16x8*)&buf[(row >> 4) * 512 + (akg * 16 + (row & 15)) * 8] = r[4 + p];
        }
    };
    auto compute = [&](const ushort_t* buf) {
        bf16x8 ah[4];
        #pragma unroll
        for (int i = 0; i < 4; ++i)
            ah[i] = __builtin_bit_cast(bf16x8, *(const u16x8*)&buf[(wr * 4 + i) * 512 + lane * 8]);
        #pragma unroll
        for (int j = 0; j < 4; ++j) {
            const bf16x8 bh = __builtin_bit_cast(bf16x8, *(const u16x8*)&buf[(8 + wc * 4 + j) * 512 + lane * 8]);
            const bf16x8 bl = __builtin_bit_cast(bf16x8, *(const u16x8*)&buf[(16 + wc * 4 + j) * 512 + lane * 8]);
            #pragma unroll
            for (int i = 0; i < 4; ++i) {
                acc[i][j] = __builtin_amdgcn_mfma_f32_16x16x32_bf16(ah[i], bh, acc[i][j], 0, 0, 0);
                acc[i][j] = __builtin_amdgcn_mfma_f32_16x16x32_bf16(ah[i], bl, acc[i][j], 0, 0, 0);
            }
        }
    };

    // prologue: buf0 <- kc0 (stall once), rB <- kc1 (in flight)
    issueTo(0, rA);
    commitFrom(rA, lds);
    issueTo(1, rB);
    __syncthreads();

    for (int kc = 0; kc < 64; kc += 2) {
        // even: buf0 ready(kc); rB holds kc+1
        if (kc + 2 < 64) issueTo(kc + 2, rA);
        compute(lds);
        commitFrom(rB, lds + 24 * 512);
        __syncthreads();
        // odd: buf1 ready(kc+1); rA holds kc+2
        if (kc + 3 < 64) issueTo(kc + 3, rB);
        compute(lds + 24 * 512);
        if (kc + 2 < 64) commitFrom(rA, lds);
        __syncthreads();
    }

    #pragma unroll
    for (int i = 0; i < 4; ++i)
        #pragma unroll
        for (int j = 0; j < 4; ++j) {
            const int col = nb * 128 + (wc * 4 + j) * 16 + (lane & 15);
            const float bv = bias[col];
            const int rbase = mb * 128 + (wr * 4 + i) * 16 + ((lane >> 4) << 2);
            #pragma unroll
            for (int r = 0; r < 4; ++r)
                att1bf[(size_t)(rbase + r) * 512 + col] = f2bf(acc[i][j][r] + bv);
        }
}

// ------------------------- fp32 GEMM (one-time h0/c0 only) -----------------
__device__ __forceinline__ void gemm_body(
    float (*As)[68], float (*Ws)[68],
    const float* __restrict__ A, int lda,
    const float* __restrict__ W, int ldw,
    float* __restrict__ C, int ldc,
    int nTile, int N, int K)
{
    const int tid = threadIdx.x;
    const int tn = tid & 15;
    const int tm = tid >> 4;
    const int n0 = nTile * 64;

    float acc[4][4] = {{0.f}};

    for (int k0 = 0; k0 < K; k0 += 32) {
        {
            int r  = tid >> 3;
            int cc = (tid & 7) * 4;
            #pragma unroll
            for (int rr = 0; rr < 64; rr += 32) {
                const float4 a = *(const float4*)&A[(size_t)(rr + r) * lda + (k0 + cc)];
                As[cc + 0][rr + r] = a.x;
                As[cc + 1][rr + r] = a.y;
                As[cc + 2][rr + r] = a.z;
                As[cc + 3][rr + r] = a.w;
            }
        }
        {
            int r  = tid >> 4;
            int cc = (tid & 15) * 4;
            #pragma unroll
            for (int rr = 0; rr < 32; rr += 16) {
                const float4 w = *(const float4*)&W[(size_t)(k0 + rr + r) * ldw + (n0 + cc)];
                *(float4*)&Ws[rr + r][cc] = w;
            }
        }
        __syncthreads();
        #pragma unroll
        for (int kk = 0; kk < 32; ++kk) {
            const float4 a = *(const float4*)&As[kk][tm * 4];
            const float4 w = *(const float4*)&Ws[kk][tn * 4];
            const float av[4] = {a.x, a.y, a.z, a.w};
            const float wv[4] = {w.x, w.y, w.z, w.w};
            #pragma unroll
            for (int i = 0; i < 4; ++i)
                #pragma unroll
                for (int j = 0; j < 4; ++j)
                    acc[i][j] = fmaf(av[i], wv[j], acc[i][j]);
        }
        __syncthreads();
    }

    #pragma unroll
    for (int i = 0; i < 4; ++i) {
        const int m = tm * 4 + i;
        #pragma unroll
        for (int j = 0; j < 4; ++j)
            C[(size_t)m * ldc + (n0 + tn * 4 + j)] = acc[i][j];
    }
}

__global__ __launch_bounds__(TB) void gemm_hc(
    const float* __restrict__ mean,
    const float* __restrict__ Wh0, const float* __restrict__ Wc0,
    float* __restrict__ h0p, float* __restrict__ c0p)
{
    __shared__ float As[32][68];
    __shared__ float Ws[32][68];
    const int ks = blockIdx.y & 7;
    const int which = blockIdx.y >> 3;
    const float* W = which ? Wc0 : Wh0;
    float* Cp = which ? c0p : h0p;
    gemm_body(As, Ws,
              mean + (size_t)ks * 256, 2048,
              W + (size_t)ks * 256 * 512, 512,
              Cp + (size_t)ks * 64 * 512, 512,
              blockIdx.x, 512, 256);
}

// ------------------------- attention scores (bf16 att1) --------------------
// grid (64, 7): b = bx, wave handles 7 p's; a2/wf hoisted to registers.
__global__ __launch_bounds__(TB) void scores_k(
    const ushort_t* __restrict__ att1bf,  // (64,196,512) bf16
    const float* __restrict__ hga_part,   // (4,64,4608), att2 = cols 0..511
    const float* __restrict__ bd,         // (512,)
    const float* __restrict__ Wfull,      // (512,)
    float* __restrict__ scores)           // (64,196)
{
    const int b = blockIdx.x;
    const int tid = threadIdx.x;
    const int wave = tid >> 6;
    const int lane = tid & 63;

    __shared__ float a2[512];
    __shared__ float wf[512];

    for (int i = tid; i < 512; i += TB) {
        float v = bd[i];
        #pragma unroll
        for (int s = 0; s < 4; ++s)
            v += hga_part[(size_t)s * 64 * 4608 + (size_t)b * 4608 + i];
        a2[i] = v;
        wf[i] = Wfull[i];
    }
    __syncthreads();

    const int k0 = lane * 8;
    float a2r[8], wfr[8];
    #pragma unroll
    for (int e = 0; e < 8; ++e) { a2r[e] = a2[k0 + e]; wfr[e] = wf[k0 + e]; }

    const int p0 = blockIdx.y * 28 + wave * 7;
    #pragma unroll
    for (int pp = 0; pp < 7; ++pp) {
        const int p = p0 + pp;
        const u16x8 v = *(const u16x8*)&att1bf[((size_t)b * 196 + p) * 512 + k0];
        float s = 0.f;
        #pragma unroll
        for (int e = 0; e < 8; ++e)
            s = fmaf(fmaxf(bf2f(v[e]) + a2r[e], 0.f), wfr[e], s);
        #pragma unroll
        for (int o = 32; o; o >>= 1) s += __shfl_xor(s, o);
        if (lane == 0) scores[b * 196 + p] = s;
    }
}

// ---------- softmax + awe (bf16 features) + gate + pack --------------------
// grid (4, 64), 512 threads: 8 waves x ~25 p's, lane covers 8 cols (u16x8).
__global__ __launch_bounds__(512) void awe_gate(
    const float* __restrict__ scores,     // (64,196)
    const ushort_t* __restrict__ fbf,     // (64,196,2048) bf16
    const float* __restrict__ hga_part,   // (4,64,4608), gpre = cols 512..2559
    const float* __restrict__ bf,         // (2048,)
    ushort_t* __restrict__ gPh, ushort_t* __restrict__ gPl)
{
    const int b = blockIdx.y, chunk = blockIdx.x;
    const int tid = threadIdx.x;
    const int q = tid >> 6, lane = tid & 63;

    __shared__ float al[196];
    __shared__ float redm[8], reds[8];
    __shared__ float smq[8][512];

    const float sv = (tid < 196) ? scores[b * 196 + tid] : -1e30f;
    float m = sv;
    #pragma unroll
    for (int o = 32; o; o >>= 1) m = fmaxf(m, __shfl_xor(m, o));
    if (lane == 0) redm[q] = m;
    __syncthreads();
    m = redm[0];
    #pragma unroll
    for (int i = 1; i < 8; ++i) m = fmaxf(m, redm[i]);

    const float e = (tid < 196) ? expf(sv - m) : 0.f;
    float s = e;
    #pragma unroll
    for (int o = 32; o; o >>= 1) s += __shfl_xor(s, o);
    if (lane == 0) reds[q] = s;
    __syncthreads();
    s = reds[0];
    #pragma unroll
    for (int i = 1; i < 8; ++i) s += reds[i];

    if (tid < 196) al[tid] = e / s;
    __syncthreads();

    // awe: wave q covers p in [q*25, min(q*25+25,196)), lane covers 8 cols
    const int col0 = chunk * 512 + lane * 8;
    const ushort_t* f = fbf + (size_t)b * 196 * 2048 + col0;
    float acc[8] = {0.f, 0.f, 0.f, 0.f, 0.f, 0.f, 0.f, 0.f};
    const int p0 = q * 25;
    const int pn = (q == 7) ? 21 : 25;
    for (int pp = 0; pp < pn; ++pp) {
        const float w = al[p0 + pp];
        const u16x8 v = *(const u16x8*)&f[(size_t)(p0 + pp) * 2048];
        #pragma unroll
        for (int ee = 0; ee < 8; ++ee)
            acc[ee] = fmaf(w, bf2f(v[ee]), acc[ee]);
    }
    *(f32x4*)&smq[q][lane * 8]     = f32x4{acc[0], acc[1], acc[2], acc[3]};
    *(f32x4*)&smq[q][lane * 8 + 4] = f32x4{acc[4], acc[5], acc[6], acc[7]};
    __syncthreads();

    const int eg = chunk * 512 + tid;
    float a = smq[0][tid];
    #pragma unroll
    for (int i = 1; i < 8; ++i) a += smq[i][tid];
    float gp = bf[eg];
    #pragma unroll
    for (int ss = 0; ss < 4; ++ss)
        gp += hga_part[(size_t)ss * 64 * 4608 + (size_t)b * 4608 + 512 + eg];
    const float gate = 1.f / (1.f + expf(-gp));
    store_pack(gPh, gPl, 64, b, eg, gate * a);
}

// ------------------------- LSTM pointwise ----------------------------------
__global__ __launch_bounds__(TB) void lstm_pw(
    const float* __restrict__ gates_part,  // (8,64,2048)
    const float* __restrict__ hga_part,    // (4,64,4608), gh = cols 2560..4607
    const float* __restrict__ eW,          // (64,20,2048), includes b_ih
    const float* __restrict__ b_hh,        // (2048,)
    int t,
    float* __restrict__ c,                 // (64,512)
    ushort_t* __restrict__ hPh, ushort_t* __restrict__ hPl,
    ushort_t* __restrict__ sPh, ushort_t* __restrict__ sPl)
{
    const int idx = blockIdx.x * TB + threadIdx.x;   // 0..32767
    const int b = idx >> 9;
    const int j = idx & 511;

    float g[4];
    #pragma unroll
    for (int comp = 0; comp < 4; ++comp) {
        const int col = comp * 512 + j;
        float v = b_hh[col] + eW[((size_t)b * 20 + t) * 2048 + col];
        #pragma unroll
        for (int s = 0; s < 8; ++s)
            v += gates_part[(size_t)s * 64 * 2048 + (size_t)b * 2048 + col];
        #pragma unroll
        for (int s = 0; s < 4; ++s)
            v += hga_part[(size_t)s * 64 * 4608 + (size_t)b * 4608 + 2560 + col];
        g[comp] = v;
    }
    const float si = 1.f / (1.f + expf(-g[0]));
    const float sf = 1.f / (1.f + expf(-g[1]));
    const float gg = tanhf(g[2]);
    const float so = 1.f / (1.f + expf(-g[3]));
    const float cn = sf * c[idx] + si * gg;
    c[idx] = cn;
    const float hn = so * tanhf(cn);
    store_pack(hPh, hPl, 16, b, j, hn);
    store_pack(sPh, sPl, 16, b * 20 + t, j, hn);
}

// ------------------------- precompute helpers ------------------------------
__global__ __launch_bounds__(TB) void mean_feat_bf(
    const ushort_t* __restrict__ fbf, float* __restrict__ mean_enc)
{
    const int b = blockIdx.y;
    const int e = blockIdx.x * TB + threadIdx.x;
    const ushort_t* f = fbf + (size_t)b * 196 * 2048 + e;
    float s = 0.f;
    #pragma unroll 4
    for (int p = 0; p < 196; ++p) s += bf2f(f[(size_t)p * 2048]);
    mean_enc[b * 2048 + e] = s * (1.f / 196.f);
}

__global__ __launch_bounds__(TB) void gather_emb_pack(
    const int* __restrict__ captions,
    const float* __restrict__ emb,
    ushort_t* __restrict__ Ph, ushort_t* __restrict__ Pl)
{
    const int bt = blockIdx.x;          // 0..1279
    const int b = bt / 20;
    const int t = bt % 20;
    const int tok = captions[b * 21 + t];
    for (int e = threadIdx.x; e < 512; e += TB)
        store_pack(Ph, Pl, 16, bt, e, emb[(size_t)tok * 512 + e]);
}

__global__ __launch_bounds__(TB) void reduce_hc(
    const float* __restrict__ h0p, const float* __restrict__ c0p,
    const float* __restrict__ bh0, const float* __restrict__ bc0,
    ushort_t* __restrict__ hPh, ushort_t* __restrict__ hPl,
    float* __restrict__ c)
{
    const int idx = blockIdx.x * TB + threadIdx.x;   // 0..65535
    const int half = idx >> 15;
    const int i = idx & 32767;
    const int j = i & 511;
    const float* P = half ? c0p : h0p;
    float v = half ? bc0[j] : bh0[j];
    #pragma unroll
    for (int s = 0; s < 8; ++s) v += P[(size_t)s * 64 * 512 + i];
    if (half) c[i] = v;
    else      store_pack(hPh, hPl, 16, i >> 9, j, v);
}

// ---------------------------------------------------------------------------
extern "C" void kernel_launch(void* const* d_in, const int* in_sizes, int n_in,
                              void* d_out, int out_size, void* d_ws, size_t ws_size,
                              hipStream_t stream)
{
    const float* features  = (const float*)d_in[0];
    const int*   captions  = (const int*)  d_in[1];
    const float* W_enc_att = (const float*)d_in[2];
    const float* b_enc_att = (const float*)d_in[3];
    const float* W_dec_att = (const float*)d_in[4];
    const float* b_dec_att = (const float*)d_in[5];
    const float* W_full    = (const float*)d_in[6];
    // d_in[7] = b_full : uniform shift -> softmax invariant, unused
    const float* emb       = (const float*)d_in[8];
    const float* W_ih      = (const float*)d_in[9];
    const float* W_hh      = (const float*)d_in[10];
    const float* b_ih      = (const float*)d_in[11];
    const float* b_hh      = (const float*)d_in[12];
    const float* W_init_h  = (const float*)d_in[13];
    const float* b_init_h  = (const float*)d_in[14];
    const float* W_init_c  = (const float*)d_in[15];
    const float* b_init_c  = (const float*)d_in[16];
    const float* W_fbeta   = (const float*)d_in[17];
    const float* b_fbeta   = (const float*)d_in[18];
    const float* W_fc      = (const float*)d_in[19];
    const float* b_fc      = (const float*)d_in[20];
    float* out = (float*)d_out;
    (void)ws_size;

    float* ws = (float*)d_ws;
    size_t off = 0;
    auto alloc  = [&](size_t n) { float* p = ws + off; off += n; return p; };
    auto ualloc = [&](size_t n) { ushort_t* p = (ushort_t*)(ws + off); off += (n + 1) / 2; return p; };

    float* eW     = alloc((size_t)64 * 20 * 2048);
    float* mean   = alloc(64 * 2048);
    float* hga    = alloc((size_t)4 * 64 * 4608);
    float* gatesp = alloc((size_t)8 * 64 * 2048);
    float* c      = alloc(64 * 512);
    float* scores = alloc(64 * 196);

    ushort_t* fbf    = ualloc((size_t)12544 * 2048);   // features bf16 (51.4 MB)
    ushort_t* att1bf = ualloc((size_t)12544 * 512);    // att1 bf16   (12.8 MB)
    ushort_t* WencH = ualloc((size_t)32 * 64 * 512);   // W_enc_att  (K2048, N512)
    ushort_t* WencL = ualloc((size_t)32 * 64 * 512);
    ushort_t* WtopH = ualloc((size_t)128 * 16 * 512);  // W_ih[:512] (K512, N2048)
    ushort_t* WtopL = ualloc((size_t)128 * 16 * 512);
    ushort_t* Wih2H = ualloc((size_t)128 * 64 * 512);  // W_ih[512:] (K2048, N2048)
    ushort_t* Wih2L = ualloc((size_t)128 * 64 * 512);
    ushort_t* WdfhH = ualloc((size_t)288 * 16 * 512);  // [Wd|Wf|Wh] (K512, N4608)
    ushort_t* WdfhL = ualloc((size_t)288 * 16 * 512);
    ushort_t* WfcH  = ualloc((size_t)632 * 16 * 512);  // W_fc       (K512, N10000->10112)
    ushort_t* WfcL  = ualloc((size_t)632 * 16 * 512);
    ushort_t* embsH = ualloc((size_t)80 * 16 * 512);   // embs  (M1280, K512)
    ushort_t* embsL = ualloc((size_t)80 * 16 * 512);
    ushort_t* hPh   = ualloc((size_t)4 * 16 * 512);    // h     (M64, K512)
    ushort_t* hPl   = ualloc((size_t)4 * 16 * 512);
    ushort_t* gPh   = ualloc((size_t)4 * 64 * 512);    // gated (M64, K2048)
    ushort_t* gPl   = ualloc((size_t)4 * 64 * 512);
    ushort_t* sPh   = ualloc((size_t)80 * 16 * 512);   // hseq  (M1280, K512)
    ushort_t* sPl   = ualloc((size_t)80 * 16 * 512);

    // one-time h0/c0 partials reuse step buffers (consumed before loop)
    float* h0p = hga;      // 8*64*512 <= 4*64*4608
    float* c0p = gatesp;   // 8*64*512 <= 8*64*2048

    // ---- pack all weights in ONE kernel ----
    PackJobs J;
    J.W[0]=W_enc_att;               J.Bh[0]=WencH; J.Bl[0]=WencL; J.Nsrc[0]=512;   J.ntCount[0]=32;  J.KC[0]=64; J.ntBase[0]=0;
    J.W[1]=W_ih;                    J.Bh[1]=WtopH; J.Bl[1]=WtopL; J.Nsrc[1]=2048;  J.ntCount[1]=128; J.KC[1]=16; J.ntBase[1]=0;
    J.W[2]=W_ih + (size_t)512*2048; J.Bh[2]=Wih2H; J.Bl[2]=Wih2L; J.Nsrc[2]=2048;  J.ntCount[2]=128; J.KC[2]=64; J.ntBase[2]=0;
    J.W[3]=W_dec_att;               J.Bh[3]=WdfhH; J.Bl[3]=WdfhL; J.Nsrc[3]=512;   J.ntCount[3]=32;  J.KC[3]=16; J.ntBase[3]=0;
    J.W[4]=W_fbeta;                 J.Bh[4]=WdfhH; J.Bl[4]=WdfhL; J.Nsrc[4]=2048;  J.ntCount[4]=128; J.KC[4]=16; J.ntBase[4]=32;
    J.W[5]=W_hh;                    J.Bh[5]=WdfhH; J.Bl[5]=WdfhL; J.Nsrc[5]=2048;  J.ntCount[5]=128; J.KC[5]=16; J.ntBase[5]=160;
    J.W[6]=W_fc;                    J.Bh[6]=WfcH;  J.Bl[6]=WfcL;  J.Nsrc[6]=10000; J.ntCount[6]=632; J.KC[6]=16; J.ntBase[6]=0;
    {
        int cum = 0;
        const int blks[7] = {512, 512, 2048, 128, 512, 512, 2528};
        for (int i = 0; i < 7; ++i) { J.cum[i] = cum; cum += blks[i]; }
        J.cum[7] = cum;
        pack_all<<<cum, TB, 0, stream>>>(J);
    }

    // ---- precompute (step-invariant) ----
    feat2bf<<<12544, TB, 0, stream>>>(features, fbf);
    gather_emb_pack<<<1280, TB, 0, stream>>>(captions, emb, embsH, embsL);
    mean_feat_bf<<<dim3(8, 64), TB, 0, stream>>>(fbf, mean);
    gemm_hc<<<dim3(8, 16), TB, 0, stream>>>(mean, W_init_h, W_init_c, h0p, c0p);
    reduce_hc<<<256, TB, 0, stream>>>(h0p, c0p, b_init_h, b_init_c, hPh, hPl, c);
    // att1 = features @ W_enc_att + b -> bf16 : (12544 x 512), K=2048
    gemm_att1<<<dim3(4, 98), TB, 0, stream>>>(fbf, WencH, WencL, b_enc_att, att1bf);
    // eW = embs @ W_ih[:512] + b_ih : (1280 x 2048), K=512
    gemm_mfma<8, 8, 2, 2><<<dim3(16, 10, 1), TB, 0, stream>>>(
        embsH, embsL, WtopH, WtopL, 16, 16, b_ih, eW, 2048, 2048, 0);

    // ---- sequential decode (round-9 proven structure, 5 dispatches/step) --
    for (int t = 0; t < 20; ++t) {
        // hga[ks] = h @ [Wd|Wf|Wh] partials : (64 x 4608), K=512 split 4
        gemm_mfma<4, 8, 2, 2><<<dim3(36, 1, 4), TB, 0, stream>>>(
            hPh, hPl, WdfhH, WdfhL, 16, 4, nullptr, hga, 4608, 4608, (size_t)64 * 4608);
        scores_k<<<dim3(64, 7), TB, 0, stream>>>(att1bf, hga, b_dec_att, W_full, scores);
        awe_gate<<<dim3(4, 64), 512, 0, stream>>>(scores, fbf, hga, b_fbeta, gPh, gPl);
        // gatesp[ks] = gated @ W_ih[512:] partials : (64 x 2048), K=2048 split 8
        gemm_mfma<4, 8, 2, 2><<<dim3(16, 1, 8), TB, 0, stream>>>(
            gPh, gPl, Wih2H, Wih2L, 64, 8, nullptr, gatesp, 2048, 2048, (size_t)64 * 2048);
        lstm_pw<<<128, TB, 0, stream>>>(gatesp, hga, eW, b_hh, t, c, hPh, hPl, sPh, sPl);
    }

    // preds = hseq @ W_fc + b_fc : (1280 x 10000), K=512
    gemm_mfma<8, 8, 2, 2><<<dim3(79, 10, 1), TB, 0, stream>>>(
        sPh, sPl, WfcH, WfcL, 16, 16, b_fc, out, 10000, 10000, 0);
}